// Round 11
// baseline (1006.343 us; speedup 1.0000x reference)
//
#include <hip/hip_runtime.h>
#include <math.h>

// ---------------------------------------------------------------------------
// MS-SSIM + MSE loss, (16,3,512,512) f32, 5 pyramid levels.
// R11: R10's 4-field FIR streaming math, restructured for wave supply.
//  - 128-thread (2-wave) blocks, wave-private LDS ring -> 12+ blocks/CU
//    available; scheduler can backfill stalls and tails.
//  - per-level band height BH: L0=32 (6144 waves), L1=16 (3072), L2..L4=8
//    (1440/336/144) -> small levels get short latency chains + more waves.
//  - 4 FIR fields (a, b, a^2+b^2, ab), products computed once at stage.
//  - 2-slot LDS double buffer, runtime parity; unroll-11 keeps FIR renaming.
//  - depth-2 global load pipeline; no fences (validated R9/R10).
// Per-wave partials, final 1-block f64 reduce. No atomics.
// ---------------------------------------------------------------------------

#define NPLANES 48

struct GaussW { float g[11]; };

typedef float v2f __attribute__((ext_vector_type(2)));

// ws float offsets: pyramids + per-WAVE partial areas
#define PYR2_OFF  4177920
#define P_L0      8355840   // 6144 pairs
#define P_L1      8368128   // 3072 pairs
#define P_L2      8374272   // 1440 pairs
#define P_L3      8377152   // 336 pairs
#define P_L4      8377824   // 144 pairs
#define P_MSE     8378112   // 6144 singles

#define C1F 1.0e-4f
#define C2F 9.0e-4f

// ---------------------------------------------------------------------------
template <int LOGW, int BH, int DO_MSE, int DO_POOL>
__global__ __launch_bounds__(128, 6) void ssim_s4(
    const float* __restrict__ x1, const float* __restrict__ x2, GaussW gw,
    float* __restrict__ partials, float* __restrict__ msep,
    float* __restrict__ d1, float* __restrict__ d2)
{
  constexpr int W = 1 << LOGW;
  constexpr int Ho = W - 10;
  constexpr int CS = (Ho + 63) >> 6;        // 64-col strips
  constexpr int RS = (Ho + BH - 1) / BH;    // BH-out-row bands
  constexpr int PW = RS * CS;
  constexpr int W2 = W >> 1;
  constexpr int TMAX = (BH + 20) / 11;      // 11-row chunks covering BH+10

  // [wave][slot][kind: 0=(a,b) 1=(ab,a^2+b^2)][col]; 4864 B per block
  __shared__ v2f rbuf[2][2][2][76];

  const int tid = threadIdx.x;
  const int wid = tid >> 6, lane = tid & 63;
  const int gwid = blockIdx.x * 2 + wid;
  const int plane = gwid / PW;
  const int rem = gwid - plane * PW;
  const int rsi = rem / CS;
  const int csi = rem - rsi * CS;

  const int gr0 = BH * rsi;
  const int c0 = 64 * csi;
  const int cb = c0 + lane;
  const int ROWS = (W - gr0 > BH + 10) ? (BH + 10) : (W - gr0);
  const int POOL_R = (rsi == RS - 1) ? ROWS : BH;   // rows this band pools
  const bool cok = cb < W;
  const bool hok = (csi < CS - 1) && (lane < 10);
  const bool hwr = lane < 10;

  const size_t pb = (size_t)plane * W * W;
  const float* q1 = x1 + pb + (size_t)gr0 * W + cb;
  const float* q2 = x2 + pb + (size_t)gr0 * W + cb;

  v2f (*rb)[2][76] = rbuf[wid];

  float mse = 0.f, sacc = 0.f, cacc = 0.f;

  // 4-field transposed FIR: f*[10] emits out row (rr-10)
  float f1[11], f2[11], f3[11], f4[11];
#pragma unroll
  for (int j = 0; j < 11; ++j) { f1[j] = 0.f; f2[j] = 0.f; f3[j] = 0.f; f4[j] = 0.f; }

#define LOADR(R, a, b, ah, bh)                                          \
  {                                                                     \
    a = 0.f; b = 0.f; ah = 0.f; bh = 0.f;                               \
    if ((R) < ROWS) {                                                   \
      size_t ro = (size_t)(R) * W;                                      \
      if (cok) { a = q1[ro]; b = q2[ro]; }                              \
      if (hok) { ah = q1[ro + 64]; bh = q2[ro + 64]; }                  \
      if (DO_MSE && (R) < POOL_R) {                                     \
        float d_ = a - b;                                               \
        mse = fmaf(d_, d_, mse);                                        \
      }                                                                 \
    }                                                                   \
  }

#define STAGER(SL, a, b, ah, bh)                                        \
  {                                                                     \
    rb[SL][0][lane] = (v2f){a, b};                                      \
    rb[SL][1][lane] = (v2f){a * b, fmaf(a, a, b * b)};                  \
    if (hwr) {                                                          \
      rb[SL][0][64 + lane] = (v2f){ah, bh};                             \
      rb[SL][1][64 + lane] = (v2f){ah * bh, fmaf(ah, ah, bh * bh)};     \
    }                                                                   \
  }

  // prologue: row 0 staged in slot 0; rows 1,2 in register pipeline
  {
    float a, b, ah, bh;
    LOADR(0, a, b, ah, bh)
    STAGER(0, a, b, ah, bh)
  }
  float aA, bA, ahA, bhA, aB, bB, ahB, bhB;
  LOADR(1, aA, bA, ahA, bhA)
  LOADR(2, aB, bB, ahB, bhB)

  for (int t = 0; t < TMAX; ++t) {
#pragma unroll
    for (int u = 0; u < 11; ++u) {
      const int rr = 11 * t + u;
      if (rr < ROWS) {
        const int sc = rr & 1, sn = sc ^ 1;

        // stage row rr+1 (loaded 2 iters ago); advance register pipeline
        if (rr + 1 < ROWS) STAGER(sn, aA, bA, ahA, bhA)
        aA = aB; bA = bB; ahA = ahB; bhA = bhB;
        LOADR(rr + 3, aB, bB, ahB, bhB)

        // ---- H-pass: 4 fields, 11 taps ----
        const v2f* rab = &rb[sc][0][lane];
        const v2f* rpq = &rb[sc][1][lane];
        float s1 = 0.f, s2 = 0.f, s3 = 0.f, s4 = 0.f;
#pragma unroll
        for (int k = 0; k < 11; ++k) {
          v2f ab = rab[k], pq = rpq[k];
          float g = gw.g[k];
          s1 = fmaf(g, ab.x, s1);
          s2 = fmaf(g, ab.y, s2);
          s4 = fmaf(g, pq.x, s4);
          s3 = fmaf(g, pq.y, s3);
        }

        // ---- V-pass: shift-accumulate (renamed over unroll-11) ----
#pragma unroll
        for (int j = 10; j >= 1; --j) {
          f1[j] = fmaf(gw.g[j], s1, f1[j - 1]);
          f2[j] = fmaf(gw.g[j], s2, f2[j - 1]);
          f3[j] = fmaf(gw.g[j], s3, f3[j - 1]);
          f4[j] = fmaf(gw.g[j], s4, f4[j - 1]);
        }
        f1[0] = gw.g[0] * s1;
        f2[0] = gw.g[0] * s2;
        f3[0] = gw.g[0] * s3;
        f4[0] = gw.g[0] * s4;

        // ---- emit SSIM/CS for out row (gr0 + rr - 10) ----
        if (rr >= 10) {
          float m1 = f1[10], m2 = f2[10], e3 = f3[10], e4 = f4[10];
          float m12 = m1 * m2;
          float msq = fmaf(m1, m1, m2 * m2);
          float v1 = 2.f * (e4 - m12) + C2F;
          float vv2 = (e3 - msq) + C2F;
          float csv = v1 * __builtin_amdgcn_rcpf(vv2);
          cacc += csv;
          sacc += csv * (2.f * m12 + C1F) *
                  __builtin_amdgcn_rcpf(msq + C1F);
        }

        // ---- fused 2x2 avgpool: pair (rr, rr+1), both slots resident ----
        if (DO_POOL && ((rr & 1) == 0) && rr < POOL_R && lane < 32) {
          v2f A0 = rb[sc][0][2 * lane], A1 = rb[sc][0][2 * lane + 1];
          v2f B0 = rb[sn][0][2 * lane], B1 = rb[sn][0][2 * lane + 1];
          int prow = (gr0 >> 1) + (rr >> 1);
          size_t ob = (size_t)plane * W2 * W2 + (size_t)prow * W2 +
                      (c0 >> 1) + lane;
          d1[ob] = 0.25f * ((A0.x + A1.x) + (B0.x + B1.x));
          d2[ob] = 0.25f * ((A0.y + A1.y) + (B0.y + B1.y));
        }
      }
    }
  }
#undef LOADR
#undef STAGER

  // column-validity mask (kills cols >= Ho, incl. cok=false lanes)
  {
    float mk = (cb < Ho) ? 1.f : 0.f;
    sacc *= mk;
    cacc *= mk;
  }

  // ---- wave reduce + per-wave partial write ----
#pragma unroll
  for (int off = 32; off; off >>= 1) {
    sacc += __shfl_down(sacc, off);
    cacc += __shfl_down(cacc, off);
    if (DO_MSE) mse += __shfl_down(mse, off);
  }
  if (lane == 0) {
    partials[2 * gwid] = sacc;
    partials[2 * gwid + 1] = cacc;
    if (DO_MSE) msep[gwid] = mse;
  }
}

// ---------------------------------------------------------------------------
__global__ __launch_bounds__(256) void final_kernel(
    const float* __restrict__ ws, float* __restrict__ out)
{
  __shared__ double sred[2][4];
  __shared__ double fin[11];  // ssim[5], cs[5], mse
  const int tid = threadIdx.x;
  const int offs[5] = {P_L0, P_L1, P_L2, P_L3, P_L4};
  const int cnts[5] = {6144, 3072, 1440, 336, 144};

  for (int l = 0; l < 5; ++l) {
    double s0 = 0.0, s1 = 0.0;
    for (int i = tid; i < cnts[l]; i += 256) {
      s0 += (double)ws[offs[l] + 2 * i];
      s1 += (double)ws[offs[l] + 2 * i + 1];
    }
#pragma unroll
    for (int off = 32; off; off >>= 1) {
      s0 += __shfl_down(s0, off);
      s1 += __shfl_down(s1, off);
    }
    if ((tid & 63) == 0) { sred[0][tid >> 6] = s0; sred[1][tid >> 6] = s1; }
    __syncthreads();
    if (tid == 0) {
      double aa = 0.0, bb = 0.0;
      for (int i = 0; i < 4; ++i) { aa += sred[0][i]; bb += sred[1][i]; }
      fin[l] = aa;
      fin[5 + l] = bb;
    }
    __syncthreads();
  }

  {
    double s0 = 0.0;
    for (int i = tid; i < 6144; i += 256) s0 += (double)ws[P_MSE + i];
#pragma unroll
    for (int off = 32; off; off >>= 1) s0 += __shfl_down(s0, off);
    if ((tid & 63) == 0) sred[0][tid >> 6] = s0;
    __syncthreads();
    if (tid == 0) {
      double aa = 0.0;
      for (int i = 0; i < 4; ++i) aa += sred[0][i];
      fin[10] = aa;
    }
    __syncthreads();
  }

  if (tid == 0) {
    const double wts[5] = {0.0448, 0.2856, 0.3001, 0.2363, 0.1333};
    const double dims[5] = {502.0, 246.0, 118.0, 54.0, 22.0};
    double mssim[5], mcs[5];
    for (int l = 0; l < 5; ++l) {
      double n = 48.0 * dims[l] * dims[l];
      mssim[l] = fin[l] / n;
      mcs[l] = fin[5 + l] / n;
    }
    // literal pytorch_msssim translation: prod(pow1[:-1] * pow2[-1])
    double p2last = pow(mssim[4], wts[4]);
    double prod = 1.0;
    for (int i = 0; i < 4; ++i) prod *= pow(mcs[i], wts[i]) * p2last;
    double msssim = prod;
    double mse = fin[10] / 12582912.0;
    out[0] = (float)(mse - msssim + 1.0);
    out[1] = (float)msssim;
  }
}

// ---------------------------------------------------------------------------
extern "C" void kernel_launch(void* const* d_in, const int* in_sizes, int n_in,
                              void* d_out, int out_size, void* d_ws, size_t ws_size,
                              hipStream_t stream)
{
  const float* rec = (const float*)d_in[0];   // reconst
  const float* orig = (const float*)d_in[1];  // original
  float* ws = (float*)d_ws;
  float* out = (float*)d_out;

  GaussW gw;
  {
    double g[11], s = 0.0;
    for (int i = 0; i < 11; ++i) {
      double x = (double)i - 5.0;
      g[i] = exp(-(x * x) / 4.5);
      s += g[i];
    }
    for (int i = 0; i < 11; ++i) gw.g[i] = (float)(g[i] / s);
  }

  // pyramid pointers
  float* A1 = ws + 0;
  float* A2 = ws + 3145728;
  float* A3 = ws + 3932160;
  float* A4 = ws + 4128768;
  float* B1 = ws + PYR2_OFF;
  float* B2 = ws + PYR2_OFF + 3145728;
  float* B3 = ws + PYR2_OFF + 3932160;
  float* B4 = ws + PYR2_OFF + 4128768;

  // blocks = waves / 2 (128-thread blocks, 2 independent waves each)
  ssim_s4<9, 32, 1, 1><<<dim3(3072), 128, 0, stream>>>(
      orig, rec, gw, ws + P_L0, ws + P_MSE, A1, B1);   // 16 bands x 8 strips
  ssim_s4<8, 16, 0, 1><<<dim3(1536), 128, 0, stream>>>(
      A1, B1, gw, ws + P_L1, nullptr, A2, B2);         // 16 bands x 4 strips
  ssim_s4<7, 8, 0, 1><<<dim3(720), 128, 0, stream>>>(
      A2, B2, gw, ws + P_L2, nullptr, A3, B3);         // 15 bands x 2 strips
  ssim_s4<6, 8, 0, 1><<<dim3(168), 128, 0, stream>>>(
      A3, B3, gw, ws + P_L3, nullptr, A4, B4);         // 7 bands x 1 strip
  ssim_s4<5, 8, 0, 0><<<dim3(72), 128, 0, stream>>>(
      A4, B4, gw, ws + P_L4, nullptr, nullptr, nullptr); // 3 bands x 1 strip

  final_kernel<<<dim3(1), dim3(256), 0, stream>>>(ws, out);
}

// Round 12
// 154.613 us; speedup vs baseline: 6.5088x; 6.5088x over previous
//
#include <hip/hip_runtime.h>
#include <math.h>

// ---------------------------------------------------------------------------
// MS-SSIM + MSE loss, (16,3,512,512) f32, 5 pyramid levels.
// R12: R5 kernel (best measured L0: 93us) + BH band decomposition for the
// small levels. Column-streaming, 256-thread blocks, per-row __syncthreads,
// 3-slot LDS ring (runtime slot idx), 5-field on-the-fly H-pass, 55-reg
// static-index FIR V-pass (NOT unrolled by 11 -- proven non-spilling at
// launch_bounds(256,4), VGPR 60). Bands: L0 16x32, L1 16x16, L2 16x8,
// L3 8x8, L4 6x4 -> 3-4x more blocks and ~2.3x shorter latency chains on
// the previously-starved small levels. Per-block partials, f64 final.
// DO NOT tighten launch_bounds: (256,4) is load-bearing (R6/R11 spilled).
// ---------------------------------------------------------------------------

#define NPLANES 48

struct GaussW { float g[11]; };

// ws float offsets: pyramids + per-BLOCK partial areas
#define PYR2_OFF  4177920
#define P_L0      8355840   // 1536 pairs
#define P_L1      8358912   // 768 pairs
#define P_L2      8360448   // 384 pairs
#define P_L3      8361216   // 96 pairs
#define P_L4      8361408   // 36 pairs
#define P_MSE     8361480   // 1536 singles

#define C1F 1.0e-4f
#define C2F 9.0e-4f

// ---------------------------------------------------------------------------
template <int LOGW, int BH, int DO_MSE, int DO_POOL>
__global__ __launch_bounds__(256, 4) void ssim_band(
    const float* __restrict__ x1, const float* __restrict__ x2, GaussW gw,
    float* __restrict__ partials, float* __restrict__ msep,
    float* __restrict__ d1, float* __restrict__ d2)
{
  constexpr int W = 1 << LOGW;
  constexpr int Ho = W - 10;
  constexpr int LOGWB = (LOGW > 8) ? 8 : LOGW;
  constexpr int WB = 1 << LOGWB;     // columns per block (per plane)
  constexpr int P = 256 >> LOGWB;    // planes per block
  constexpr int STRIDE = WB + 12;
  constexpr int W2 = W >> 1;

  __shared__ float rowbuf[3][2 * P][STRIDE];
  __shared__ float red[3][4];

  const int tid = threadIdx.x;
  const int p = tid >> LOGWB;
  const int col = tid & (WB - 1);
  const int bx = blockIdx.x, by = blockIdx.y, bz = blockIdx.z;
  const int gcol = bx * WB + col;            // plane-local column
  const int plane = bz * P + p;
  const size_t pb = (size_t)plane * W * W;
  const float* q1 = x1 + pb + gcol;
  const float* q2 = x2 + pb + gcol;
  const int gr0 = BH * by;
  const int ROWS = ((W - gr0) < (BH + 10)) ? (W - gr0) : (BH + 10);
  const bool xtra = (bx * WB + WB + col) < W;  // extra halo col exists

  // transposed-FIR accumulators: acc*[10] emits out row (rr-10)
  float acc0[11], acc1[11], acc2[11], acc3[11], acc4[11];
#pragma unroll
  for (int j = 0; j < 11; ++j) {
    acc0[j] = 0.f; acc1[j] = 0.f; acc2[j] = 0.f; acc3[j] = 0.f; acc4[j] = 0.f;
  }

  float mse_acc = 0.f, ssim_acc = 0.f, cs_acc = 0.f;

  // ---- prologue: row 0 into slot 0 ----
  {
    size_t ro = (size_t)gr0 * W;
    float a = q1[ro], b = q2[ro];
    float ae = 0.f, be = 0.f;
    if (col < 12 && xtra) { ae = q1[ro + WB]; be = q2[ro + WB]; }
    if (DO_MSE) { float d = a - b; mse_acc = d * d; }
    rowbuf[0][2 * p][col] = a;
    rowbuf[0][2 * p + 1][col] = b;
    if (col < 12) {
      rowbuf[0][2 * p][WB + col] = ae;
      rowbuf[0][2 * p + 1][WB + col] = be;
    }
  }
  __syncthreads();

  int cur = 0;
  for (int rr = 0; rr < ROWS; ++rr) {
    int nxt = cur + 1; if (nxt == 3) nxt = 0;
    int prv = cur - 1; if (prv < 0) prv = 2;
    const bool have = (rr + 1) < ROWS;  // uniform

    // issue next row's global loads early (hide HBM under compute)
    float a = 0.f, b = 0.f, ae = 0.f, be = 0.f;
    if (have) {
      size_t ro = (size_t)(gr0 + rr + 1) * W;
      a = q1[ro]; b = q2[ro];
      if (col < 12 && xtra) { ae = q1[ro + WB]; be = q2[ro + WB]; }
    }

    // ---- H-pass: 11-tap window from rowbuf[cur] ----
    const float* r1 = &rowbuf[cur][2 * p][col];
    const float* r2 = &rowbuf[cur][2 * p + 1][col];
    float s1 = 0.f, s2 = 0.f, s11 = 0.f, s22 = 0.f, s12 = 0.f;
#pragma unroll
    for (int k = 0; k < 11; ++k) {
      float av = r1[k], bv = r2[k], w = gw.g[k];
      float wa = w * av, wb = w * bv;
      s1 += wa; s2 += wb;
      s11 = fmaf(wa, av, s11);
      s22 = fmaf(wb, bv, s22);
      s12 = fmaf(wa, bv, s12);
    }

    // ---- V-pass: shift-accumulate (static indices) ----
#pragma unroll
    for (int j = 10; j >= 1; --j) {
      acc0[j] = fmaf(gw.g[j], s1, acc0[j - 1]);
      acc1[j] = fmaf(gw.g[j], s2, acc1[j - 1]);
      acc2[j] = fmaf(gw.g[j], s11, acc2[j - 1]);
      acc3[j] = fmaf(gw.g[j], s22, acc3[j - 1]);
      acc4[j] = fmaf(gw.g[j], s12, acc4[j - 1]);
    }
    acc0[0] = gw.g[0] * s1;
    acc1[0] = gw.g[0] * s2;
    acc2[0] = gw.g[0] * s11;
    acc3[0] = gw.g[0] * s22;
    acc4[0] = gw.g[0] * s12;

    // ---- emit SSIM/CS for out row (gr0 + rr - 10); ROWS bounds rows ----
    if (rr >= 10 && gcol < Ho) {
      float m1 = acc0[10], m2 = acc1[10];
      float m1sq = m1 * m1, m2sq = m2 * m2, m12 = m1 * m2;
      float v1 = 2.f * (acc4[10] - m12) + C2F;
      float v2 = (acc2[10] - m1sq) + (acc3[10] - m2sq) + C2F;
      float csv = v1 * __builtin_amdgcn_rcpf(v2);
      cs_acc += csv;
      ssim_acc += csv * (2.f * m12 + C1F) *
                  __builtin_amdgcn_rcpf(m1sq + m2sq + C1F);
    }

    // ---- fused 2x2 avgpool on raw row pair (prv, cur) ----
    if (DO_POOL && (rr & 1) && rr < BH && col < (WB / 2)) {
      float a00 = rowbuf[prv][2 * p][2 * col], a01 = rowbuf[prv][2 * p][2 * col + 1];
      float a10 = rowbuf[cur][2 * p][2 * col], a11 = rowbuf[cur][2 * p][2 * col + 1];
      float b00 = rowbuf[prv][2 * p + 1][2 * col], b01 = rowbuf[prv][2 * p + 1][2 * col + 1];
      float b10 = rowbuf[cur][2 * p + 1][2 * col], b11 = rowbuf[cur][2 * p + 1][2 * col + 1];
      int orow = (gr0 >> 1) + (rr >> 1);
      size_t ob = (size_t)plane * W2 * W2 + (size_t)orow * W2 + bx * (WB / 2) + col;
      d1[ob] = 0.25f * ((a00 + a01) + (a10 + a11));
      d2[ob] = 0.25f * ((b00 + b01) + (b10 + b11));
    }

    // ---- stage next row into slot nxt ----
    if (have) {
      if (DO_MSE && (rr + 1) < BH) { float d = a - b; mse_acc = fmaf(d, d, mse_acc); }
      rowbuf[nxt][2 * p][col] = a;
      rowbuf[nxt][2 * p + 1][col] = b;
      if (col < 12) {
        rowbuf[nxt][2 * p][WB + col] = ae;
        rowbuf[nxt][2 * p + 1][WB + col] = be;
      }
      __syncthreads();
    }
    cur = nxt;
  }

  // ---- block reduce (ssim, cs, mse) ----
#pragma unroll
  for (int off = 32; off; off >>= 1) {
    ssim_acc += __shfl_down(ssim_acc, off);
    cs_acc += __shfl_down(cs_acc, off);
    if (DO_MSE) mse_acc += __shfl_down(mse_acc, off);
  }
  int wave = tid >> 6, lane = tid & 63;
  if (lane == 0) {
    red[0][wave] = ssim_acc;
    red[1][wave] = cs_acc;
    if (DO_MSE) red[2][wave] = mse_acc;
  }
  __syncthreads();
  if (tid == 0) {
    float s = 0.f, cc = 0.f, m = 0.f;
#pragma unroll
    for (int i = 0; i < 4; ++i) {
      s += red[0][i];
      cc += red[1][i];
      if (DO_MSE) m += red[2][i];
    }
    int bi = (bz * gridDim.y + by) * gridDim.x + bx;
    partials[2 * bi] = s;
    partials[2 * bi + 1] = cc;
    if (DO_MSE) msep[bi] = m;
  }
}

// ---------------------------------------------------------------------------
__global__ __launch_bounds__(256) void final_kernel(
    const float* __restrict__ ws, float* __restrict__ out)
{
  __shared__ double sred[2][4];
  __shared__ double fin[11];  // ssim[5], cs[5], mse
  const int tid = threadIdx.x;
  const int offs[5] = {P_L0, P_L1, P_L2, P_L3, P_L4};
  const int cnts[5] = {1536, 768, 384, 96, 36};

  for (int l = 0; l < 5; ++l) {
    double s0 = 0.0, s1 = 0.0;
    for (int i = tid; i < cnts[l]; i += 256) {
      s0 += (double)ws[offs[l] + 2 * i];
      s1 += (double)ws[offs[l] + 2 * i + 1];
    }
#pragma unroll
    for (int off = 32; off; off >>= 1) {
      s0 += __shfl_down(s0, off);
      s1 += __shfl_down(s1, off);
    }
    if ((tid & 63) == 0) { sred[0][tid >> 6] = s0; sred[1][tid >> 6] = s1; }
    __syncthreads();
    if (tid == 0) {
      double aa = 0.0, bb = 0.0;
      for (int i = 0; i < 4; ++i) { aa += sred[0][i]; bb += sred[1][i]; }
      fin[l] = aa;
      fin[5 + l] = bb;
    }
    __syncthreads();
  }

  {
    double s0 = 0.0;
    for (int i = tid; i < 1536; i += 256) s0 += (double)ws[P_MSE + i];
#pragma unroll
    for (int off = 32; off; off >>= 1) s0 += __shfl_down(s0, off);
    if ((tid & 63) == 0) sred[0][tid >> 6] = s0;
    __syncthreads();
    if (tid == 0) {
      double aa = 0.0;
      for (int i = 0; i < 4; ++i) aa += sred[0][i];
      fin[10] = aa;
    }
    __syncthreads();
  }

  if (tid == 0) {
    const double wts[5] = {0.0448, 0.2856, 0.3001, 0.2363, 0.1333};
    const double dims[5] = {502.0, 246.0, 118.0, 54.0, 22.0};
    double mssim[5], mcs[5];
    for (int l = 0; l < 5; ++l) {
      double n = 48.0 * dims[l] * dims[l];
      mssim[l] = fin[l] / n;
      mcs[l] = fin[5 + l] / n;
    }
    // literal pytorch_msssim translation: prod(pow1[:-1] * pow2[-1])
    double p2last = pow(mssim[4], wts[4]);
    double prod = 1.0;
    for (int i = 0; i < 4; ++i) prod *= pow(mcs[i], wts[i]) * p2last;
    double msssim = prod;
    double mse = fin[10] / 12582912.0;
    out[0] = (float)(mse - msssim + 1.0);
    out[1] = (float)msssim;
  }
}

// ---------------------------------------------------------------------------
extern "C" void kernel_launch(void* const* d_in, const int* in_sizes, int n_in,
                              void* d_out, int out_size, void* d_ws, size_t ws_size,
                              hipStream_t stream)
{
  const float* rec = (const float*)d_in[0];   // reconst
  const float* orig = (const float*)d_in[1];  // original
  float* ws = (float*)d_ws;
  float* out = (float*)d_out;

  GaussW gw;
  {
    double g[11], s = 0.0;
    for (int i = 0; i < 11; ++i) {
      double x = (double)i - 5.0;
      g[i] = exp(-(x * x) / 4.5);
      s += g[i];
    }
    for (int i = 0; i < 11; ++i) gw.g[i] = (float)(g[i] / s);
  }

  // pyramid pointers
  float* A1 = ws + 0;
  float* A2 = ws + 3145728;
  float* A3 = ws + 3932160;
  float* A4 = ws + 4128768;
  float* B1 = ws + PYR2_OFF;
  float* B2 = ws + PYR2_OFF + 3145728;
  float* B3 = ws + PYR2_OFF + 3932160;
  float* B4 = ws + PYR2_OFF + 4128768;

  // grid = (col strips, bands, planes/P); band heights tuned per level
  ssim_band<9, 32, 1, 1><<<dim3(2, 16, 48), 256, 0, stream>>>(
      orig, rec, gw, ws + P_L0, ws + P_MSE, A1, B1);    // 1536 blocks
  ssim_band<8, 16, 0, 1><<<dim3(1, 16, 48), 256, 0, stream>>>(
      A1, B1, gw, ws + P_L1, nullptr, A2, B2);          // 768 blocks
  ssim_band<7, 8, 0, 1><<<dim3(1, 16, 24), 256, 0, stream>>>(
      A2, B2, gw, ws + P_L2, nullptr, A3, B3);          // 384 blocks
  ssim_band<6, 8, 0, 1><<<dim3(1, 8, 12), 256, 0, stream>>>(
      A3, B3, gw, ws + P_L3, nullptr, A4, B4);          // 96 blocks
  ssim_band<5, 4, 0, 0><<<dim3(1, 6, 6), 256, 0, stream>>>(
      A4, B4, gw, ws + P_L4, nullptr, nullptr, nullptr); // 36 blocks

  final_kernel<<<dim3(1), dim3(256), 0, stream>>>(ws, out);
}

// Round 13
// 143.363 us; speedup vs baseline: 7.0195x; 1.0785x over previous
//
#include <hip/hip_runtime.h>
#include <math.h>

// ---------------------------------------------------------------------------
// MS-SSIM + MSE loss, (16,3,512,512) f32, 5 pyramid levels.
// R13 = R12 + (a,b) interleaved as v2f in LDS: H-pass = 11 ds_read_b64
// instead of 22 ds_read_b32 (halves LDS issue); pool reads 8->4 ops,
// stage writes 2->1. Everything else identical to R12 (best: 155us).
// Column-streaming, 256-thread blocks, per-row __syncthreads, 3-slot LDS
// ring, 5-field on-the-fly H-pass, 55-reg static FIR V-pass. Bands:
// L0 16x32, L1 16x16, L2 16x8, L3 8x8, L4 6x4. Per-block partials, f64
// final. DO NOT tighten launch_bounds: (256,4) is load-bearing (R6/R11
// spilled at tighter bounds -> scratch traffic, 2-5x slowdowns).
// ---------------------------------------------------------------------------

#define NPLANES 48

struct GaussW { float g[11]; };

typedef float v2f __attribute__((ext_vector_type(2)));

// ws float offsets: pyramids + per-BLOCK partial areas
#define PYR2_OFF  4177920
#define P_L0      8355840   // 1536 pairs
#define P_L1      8358912   // 768 pairs
#define P_L2      8360448   // 384 pairs
#define P_L3      8361216   // 96 pairs
#define P_L4      8361408   // 36 pairs
#define P_MSE     8361480   // 1536 singles

#define C1F 1.0e-4f
#define C2F 9.0e-4f

// ---------------------------------------------------------------------------
template <int LOGW, int BH, int DO_MSE, int DO_POOL>
__global__ __launch_bounds__(256, 4) void ssim_band(
    const float* __restrict__ x1, const float* __restrict__ x2, GaussW gw,
    float* __restrict__ partials, float* __restrict__ msep,
    float* __restrict__ d1, float* __restrict__ d2)
{
  constexpr int W = 1 << LOGW;
  constexpr int Ho = W - 10;
  constexpr int LOGWB = (LOGW > 8) ? 8 : LOGW;
  constexpr int WB = 1 << LOGWB;     // columns per block (per plane)
  constexpr int P = 256 >> LOGWB;    // planes per block
  constexpr int STRIDE = WB + 12;
  constexpr int W2 = W >> 1;

  // (a,b) interleaved: one ds_read_b64 per tap instead of 2x ds_read_b32
  __shared__ v2f vbuf[3][P][STRIDE];
  __shared__ float red[3][4];

  const int tid = threadIdx.x;
  const int p = tid >> LOGWB;
  const int col = tid & (WB - 1);
  const int bx = blockIdx.x, by = blockIdx.y, bz = blockIdx.z;
  const int gcol = bx * WB + col;            // plane-local column
  const int plane = bz * P + p;
  const size_t pb = (size_t)plane * W * W;
  const float* q1 = x1 + pb + gcol;
  const float* q2 = x2 + pb + gcol;
  const int gr0 = BH * by;
  const int ROWS = ((W - gr0) < (BH + 10)) ? (W - gr0) : (BH + 10);
  const bool xtra = (bx * WB + WB + col) < W;  // extra halo col exists

  // transposed-FIR accumulators: acc*[10] emits out row (rr-10)
  float acc0[11], acc1[11], acc2[11], acc3[11], acc4[11];
#pragma unroll
  for (int j = 0; j < 11; ++j) {
    acc0[j] = 0.f; acc1[j] = 0.f; acc2[j] = 0.f; acc3[j] = 0.f; acc4[j] = 0.f;
  }

  float mse_acc = 0.f, ssim_acc = 0.f, cs_acc = 0.f;

  // ---- prologue: row 0 into slot 0 ----
  {
    size_t ro = (size_t)gr0 * W;
    float a = q1[ro], b = q2[ro];
    float ae = 0.f, be = 0.f;
    if (col < 12 && xtra) { ae = q1[ro + WB]; be = q2[ro + WB]; }
    if (DO_MSE) { float d = a - b; mse_acc = d * d; }
    vbuf[0][p][col] = (v2f){a, b};
    if (col < 12) vbuf[0][p][WB + col] = (v2f){ae, be};
  }
  __syncthreads();

  int cur = 0;
  for (int rr = 0; rr < ROWS; ++rr) {
    int nxt = cur + 1; if (nxt == 3) nxt = 0;
    int prv = cur - 1; if (prv < 0) prv = 2;
    const bool have = (rr + 1) < ROWS;  // uniform

    // issue next row's global loads early (hide HBM under compute)
    float a = 0.f, b = 0.f, ae = 0.f, be = 0.f;
    if (have) {
      size_t ro = (size_t)(gr0 + rr + 1) * W;
      a = q1[ro]; b = q2[ro];
      if (col < 12 && xtra) { ae = q1[ro + WB]; be = q2[ro + WB]; }
    }

    // ---- H-pass: 11-tap window, one b64 read per tap ----
    const v2f* r = &vbuf[cur][p][col];
    float s1 = 0.f, s2 = 0.f, s11 = 0.f, s22 = 0.f, s12 = 0.f;
#pragma unroll
    for (int k = 0; k < 11; ++k) {
      v2f ab = r[k];
      float av = ab.x, bv = ab.y, w = gw.g[k];
      float wa = w * av, wb = w * bv;
      s1 += wa; s2 += wb;
      s11 = fmaf(wa, av, s11);
      s22 = fmaf(wb, bv, s22);
      s12 = fmaf(wa, bv, s12);
    }

    // ---- V-pass: shift-accumulate (static indices) ----
#pragma unroll
    for (int j = 10; j >= 1; --j) {
      acc0[j] = fmaf(gw.g[j], s1, acc0[j - 1]);
      acc1[j] = fmaf(gw.g[j], s2, acc1[j - 1]);
      acc2[j] = fmaf(gw.g[j], s11, acc2[j - 1]);
      acc3[j] = fmaf(gw.g[j], s22, acc3[j - 1]);
      acc4[j] = fmaf(gw.g[j], s12, acc4[j - 1]);
    }
    acc0[0] = gw.g[0] * s1;
    acc1[0] = gw.g[0] * s2;
    acc2[0] = gw.g[0] * s11;
    acc3[0] = gw.g[0] * s22;
    acc4[0] = gw.g[0] * s12;

    // ---- emit SSIM/CS for out row (gr0 + rr - 10); ROWS bounds rows ----
    if (rr >= 10 && gcol < Ho) {
      float m1 = acc0[10], m2 = acc1[10];
      float m1sq = m1 * m1, m2sq = m2 * m2, m12 = m1 * m2;
      float v1 = 2.f * (acc4[10] - m12) + C2F;
      float v2 = (acc2[10] - m1sq) + (acc3[10] - m2sq) + C2F;
      float csv = v1 * __builtin_amdgcn_rcpf(v2);
      cs_acc += csv;
      ssim_acc += csv * (2.f * m12 + C1F) *
                  __builtin_amdgcn_rcpf(m1sq + m2sq + C1F);
    }

    // ---- fused 2x2 avgpool on raw row pair (prv, cur) ----
    if (DO_POOL && (rr & 1) && rr < BH && col < (WB / 2)) {
      v2f x0 = vbuf[prv][p][2 * col], x1v = vbuf[prv][p][2 * col + 1];
      v2f y0 = vbuf[cur][p][2 * col], y1v = vbuf[cur][p][2 * col + 1];
      int orow = (gr0 >> 1) + (rr >> 1);
      size_t ob = (size_t)plane * W2 * W2 + (size_t)orow * W2 + bx * (WB / 2) + col;
      d1[ob] = 0.25f * ((x0.x + x1v.x) + (y0.x + y1v.x));
      d2[ob] = 0.25f * ((x0.y + x1v.y) + (y0.y + y1v.y));
    }

    // ---- stage next row into slot nxt ----
    if (have) {
      if (DO_MSE && (rr + 1) < BH) { float d = a - b; mse_acc = fmaf(d, d, mse_acc); }
      vbuf[nxt][p][col] = (v2f){a, b};
      if (col < 12) vbuf[nxt][p][WB + col] = (v2f){ae, be};
      __syncthreads();
    }
    cur = nxt;
  }

  // ---- block reduce (ssim, cs, mse) ----
#pragma unroll
  for (int off = 32; off; off >>= 1) {
    ssim_acc += __shfl_down(ssim_acc, off);
    cs_acc += __shfl_down(cs_acc, off);
    if (DO_MSE) mse_acc += __shfl_down(mse_acc, off);
  }
  int wave = tid >> 6, lane = tid & 63;
  if (lane == 0) {
    red[0][wave] = ssim_acc;
    red[1][wave] = cs_acc;
    if (DO_MSE) red[2][wave] = mse_acc;
  }
  __syncthreads();
  if (tid == 0) {
    float s = 0.f, cc = 0.f, m = 0.f;
#pragma unroll
    for (int i = 0; i < 4; ++i) {
      s += red[0][i];
      cc += red[1][i];
      if (DO_MSE) m += red[2][i];
    }
    int bi = (bz * gridDim.y + by) * gridDim.x + bx;
    partials[2 * bi] = s;
    partials[2 * bi + 1] = cc;
    if (DO_MSE) msep[bi] = m;
  }
}

// ---------------------------------------------------------------------------
__global__ __launch_bounds__(256) void final_kernel(
    const float* __restrict__ ws, float* __restrict__ out)
{
  __shared__ double sred[2][4];
  __shared__ double fin[11];  // ssim[5], cs[5], mse
  const int tid = threadIdx.x;
  const int offs[5] = {P_L0, P_L1, P_L2, P_L3, P_L4};
  const int cnts[5] = {1536, 768, 384, 96, 36};

  for (int l = 0; l < 5; ++l) {
    double s0 = 0.0, s1 = 0.0;
    for (int i = tid; i < cnts[l]; i += 256) {
      s0 += (double)ws[offs[l] + 2 * i];
      s1 += (double)ws[offs[l] + 2 * i + 1];
    }
#pragma unroll
    for (int off = 32; off; off >>= 1) {
      s0 += __shfl_down(s0, off);
      s1 += __shfl_down(s1, off);
    }
    if ((tid & 63) == 0) { sred[0][tid >> 6] = s0; sred[1][tid >> 6] = s1; }
    __syncthreads();
    if (tid == 0) {
      double aa = 0.0, bb = 0.0;
      for (int i = 0; i < 4; ++i) { aa += sred[0][i]; bb += sred[1][i]; }
      fin[l] = aa;
      fin[5 + l] = bb;
    }
    __syncthreads();
  }

  {
    double s0 = 0.0;
    for (int i = tid; i < 1536; i += 256) s0 += (double)ws[P_MSE + i];
#pragma unroll
    for (int off = 32; off; off >>= 1) s0 += __shfl_down(s0, off);
    if ((tid & 63) == 0) sred[0][tid >> 6] = s0;
    __syncthreads();
    if (tid == 0) {
      double aa = 0.0;
      for (int i = 0; i < 4; ++i) aa += sred[0][i];
      fin[10] = aa;
    }
    __syncthreads();
  }

  if (tid == 0) {
    const double wts[5] = {0.0448, 0.2856, 0.3001, 0.2363, 0.1333};
    const double dims[5] = {502.0, 246.0, 118.0, 54.0, 22.0};
    double mssim[5], mcs[5];
    for (int l = 0; l < 5; ++l) {
      double n = 48.0 * dims[l] * dims[l];
      mssim[l] = fin[l] / n;
      mcs[l] = fin[5 + l] / n;
    }
    // literal pytorch_msssim translation: prod(pow1[:-1] * pow2[-1])
    double p2last = pow(mssim[4], wts[4]);
    double prod = 1.0;
    for (int i = 0; i < 4; ++i) prod *= pow(mcs[i], wts[i]) * p2last;
    double msssim = prod;
    double mse = fin[10] / 12582912.0;
    out[0] = (float)(mse - msssim + 1.0);
    out[1] = (float)msssim;
  }
}

// ---------------------------------------------------------------------------
extern "C" void kernel_launch(void* const* d_in, const int* in_sizes, int n_in,
                              void* d_out, int out_size, void* d_ws, size_t ws_size,
                              hipStream_t stream)
{
  const float* rec = (const float*)d_in[0];   // reconst
  const float* orig = (const float*)d_in[1];  // original
  float* ws = (float*)d_ws;
  float* out = (float*)d_out;

  GaussW gw;
  {
    double g[11], s = 0.0;
    for (int i = 0; i < 11; ++i) {
      double x = (double)i - 5.0;
      g[i] = exp(-(x * x) / 4.5);
      s += g[i];
    }
    for (int i = 0; i < 11; ++i) gw.g[i] = (float)(g[i] / s);
  }

  // pyramid pointers
  float* A1 = ws + 0;
  float* A2 = ws + 3145728;
  float* A3 = ws + 3932160;
  float* A4 = ws + 4128768;
  float* B1 = ws + PYR2_OFF;
  float* B2 = ws + PYR2_OFF + 3145728;
  float* B3 = ws + PYR2_OFF + 3932160;
  float* B4 = ws + PYR2_OFF + 4128768;

  // grid = (col strips, bands, planes/P); band heights tuned per level
  ssim_band<9, 32, 1, 1><<<dim3(2, 16, 48), 256, 0, stream>>>(
      orig, rec, gw, ws + P_L0, ws + P_MSE, A1, B1);    // 1536 blocks
  ssim_band<8, 16, 0, 1><<<dim3(1, 16, 48), 256, 0, stream>>>(
      A1, B1, gw, ws + P_L1, nullptr, A2, B2);          // 768 blocks
  ssim_band<7, 8, 0, 1><<<dim3(1, 16, 24), 256, 0, stream>>>(
      A2, B2, gw, ws + P_L2, nullptr, A3, B3);          // 384 blocks
  ssim_band<6, 8, 0, 1><<<dim3(1, 8, 12), 256, 0, stream>>>(
      A3, B3, gw, ws + P_L3, nullptr, A4, B4);          // 96 blocks
  ssim_band<5, 4, 0, 0><<<dim3(1, 6, 6), 256, 0, stream>>>(
      A4, B4, gw, ws + P_L4, nullptr, nullptr, nullptr); // 36 blocks

  final_kernel<<<dim3(1), dim3(256), 0, stream>>>(ws, out);
}